// Round 9
// baseline (163.052 us; speedup 1.0000x reference)
//
#include <hip/hip_runtime.h>
#include <hip/hip_bf16.h>

// Problem constants (from reference)
#define B 16
#define C 128
#define H 192
#define W 192
#define HID 32
#define K 2
#define PLANE (H*W)           // 36864
#define NPLANES (B*C)         // 2048

// conv tiling
#define TBLK 384              // threads per conv block (6 waves)
#define TROWS 32              // output rows per block
#define SROWS 34              // staged rows (with halo)
#define LDST 196              // LDS row stride in floats (49 float4)
#define SEGS (H / TROWS)      // 6 blocks per plane

typedef float floatx4 __attribute__((ext_vector_type(4)));

// ---------------- Kernel 1: global average pool per (b,c) plane ----------------
__global__ __launch_bounds__(256) void pool_kernel(const float* __restrict__ x,
                                                   float* __restrict__ pooled) {
    const int plane = blockIdx.x;  // b*C + c
    const float4* px4 = (const float4*)(x + (size_t)plane * PLANE);  // 9216 float4
    float s = 0.f;
    for (int i = threadIdx.x; i < PLANE / 4; i += 256) {
        float4 v = px4[i];
        s += v.x + v.y + v.z + v.w;
    }
    for (int off = 32; off; off >>= 1) s += __shfl_down(s, off, 64);
    __shared__ float wsum[4];
    const int lane = threadIdx.x & 63, wid = threadIdx.x >> 6;
    if (lane == 0) wsum[wid] = s;
    __syncthreads();
    if (threadIdx.x == 0) {
        pooled[plane] = (wsum[0] + wsum[1] + wsum[2] + wsum[3]) * (1.0f / (float)PLANE);
    }
}

// ---------------- Kernel 2: selector MLP + softmax + weight combine ----------------
__global__ __launch_bounds__(512) void selector_kernel(const float* __restrict__ pooled,
                                                       const float* __restrict__ w1,
                                                       const float* __restrict__ b1,
                                                       const float* __restrict__ w2,
                                                       const float* __restrict__ b2,
                                                       const float* __restrict__ wb,
                                                       float* __restrict__ cw) {
    __shared__ float h[B][HID];
    __shared__ float attn[B][K];
    const int tid = threadIdx.x;

    {
        const int b = tid >> 5, j = tid & 31;
        float s = b1[j];
        const float* pb = pooled + b * C;
        const float* wj = w1 + j * C;
        #pragma unroll 8
        for (int c = 0; c < C; ++c) s += pb[c] * wj[c];
        h[b][j] = fmaxf(s, 0.f);
    }
    __syncthreads();
    if (tid < B * K) {
        const int b = tid >> 1, k = tid & 1;
        float s = b2[k];
        const float* wk = w2 + k * HID;
        #pragma unroll
        for (int j = 0; j < HID; ++j) s += h[b][j] * wk[j];
        attn[b][k] = s;
    }
    __syncthreads();
    if (tid < B) {
        const float a0 = attn[tid][0], a1 = attn[tid][1];
        const float m = fmaxf(a0, a1);
        const float e0 = __expf(a0 - m), e1 = __expf(a1 - m);
        const float inv = 1.f / (e0 + e1);
        attn[tid][0] = e0 * inv;
        attn[tid][1] = e1 * inv;
    }
    __syncthreads();
    for (int i = tid; i < B * C * 9; i += 512) {
        const int b = i / (C * 9);
        const int ci = i % (C * 9);
        cw[i] = attn[b][0] * wb[ci] + attn[b][1] * wb[C * 9 + ci];
    }
}

// ---------------- Kernel 3: depthwise 3x3 conv (pad 1) + bias, LDS-staged ----------------
// Block = 384 threads stages a 34-row x 192-col input tile into LDS ONCE
// (perfectly coalesced dwordx4, each cache line probed exactly once ->
// broke the ~3 TB/s L1 tag-lookup wall: 216 -> 163 us, proven R8),
// then computes 32 output rows from LDS. Thread = 4-wide x 4-tall tile.
// Planes iterate in REVERSE: pool streams 0->2047 and leaves the ~250 MB
// tail of x resident in Infinity Cache; conv reads that tail first
// (proven FETCH 302->162 MB in R5). NT stores keep the write stream from
// evicting x.
__global__ __launch_bounds__(TBLK) void conv_kernel(const float* __restrict__ x,
                                                    const float* __restrict__ cw,
                                                    const float* __restrict__ bias,
                                                    float* __restrict__ out) {
    __shared__ float lds[SROWS * LDST];

    const int bid   = blockIdx.x;
    const int plane = (NPLANES - 1) - (bid / SEGS);  // reverse, block-uniform
    const int seg   = bid % SEGS;
    const int tid   = threadIdx.x;
    const int c     = plane & (C - 1);
    const int y0    = seg * TROWS;

    const float* w = cw + plane * 9;
    const float w00 = w[0], w01 = w[1], w02 = w[2];
    const float w10 = w[3], w11 = w[4], w12 = w[5];
    const float w20 = w[6], w21 = w[7], w22 = w[8];
    const float bv = bias[c];

    // ---- stage 34 rows x 192 cols (48 float4 per row) into LDS ----
    const float4* px4 = (const float4*)(x + (size_t)plane * PLANE);
    float4* lds4 = (float4*)lds;
    #pragma unroll
    for (int k = 0; k < 5; ++k) {
        const int idx = tid + k * TBLK;          // 0..1631 (34*48)
        if (idx < SROWS * 48) {
            const int row  = idx / 48;           // staged row
            const int col4 = idx % 48;
            const int gRow = y0 - 1 + row;       // global image row
            float4 v = make_float4(0.f, 0.f, 0.f, 0.f);
            if (gRow >= 0 && gRow < H) v = px4[gRow * 48 + col4];
            lds4[row * 49 + col4] = v;
        }
    }
    __syncthreads();

    // ---- compute: thread = 4-wide x 4-tall ----
    const int xq   = tid % 48;      // col strip
    const int band = tid / 48;      // 0..7 (4 rows each)
    const int x0   = xq * 4;

    float acc[4][4];
    #pragma unroll
    for (int j = 0; j < 4; ++j) {
        acc[j][0] = bv; acc[j][1] = bv; acc[j][2] = bv; acc[j][3] = bv;
    }

    #pragma unroll
    for (int i = 0; i < 6; ++i) {
        const int sr = band * 4 + i;            // staged row index
        const float* lr = lds + sr * LDST;
        const floatx4 cur = *(const floatx4*)(lr + x0);
        const float v0 = (xq > 0)  ? lr[x0 - 1] : 0.f;
        const float v5 = (xq < 47) ? lr[x0 + 4] : 0.f;
        const float v1 = cur.x, v2 = cur.y, v3 = cur.z, v4 = cur.w;

        // staged row sr: TOP tap of out j=i, MID of j=i-1, BOTTOM of j=i-2
        if (i < 4) {
            acc[i][0] = fmaf(w00, v0, fmaf(w01, v1, fmaf(w02, v2, acc[i][0])));
            acc[i][1] = fmaf(w00, v1, fmaf(w01, v2, fmaf(w02, v3, acc[i][1])));
            acc[i][2] = fmaf(w00, v2, fmaf(w01, v3, fmaf(w02, v4, acc[i][2])));
            acc[i][3] = fmaf(w00, v3, fmaf(w01, v4, fmaf(w02, v5, acc[i][3])));
        }
        if (i >= 1 && i <= 4) {
            acc[i-1][0] = fmaf(w10, v0, fmaf(w11, v1, fmaf(w12, v2, acc[i-1][0])));
            acc[i-1][1] = fmaf(w10, v1, fmaf(w11, v2, fmaf(w12, v3, acc[i-1][1])));
            acc[i-1][2] = fmaf(w10, v2, fmaf(w11, v3, fmaf(w12, v4, acc[i-1][2])));
            acc[i-1][3] = fmaf(w10, v3, fmaf(w11, v4, fmaf(w12, v5, acc[i-1][3])));
        }
        if (i >= 2) {
            acc[i-2][0] = fmaf(w20, v0, fmaf(w21, v1, fmaf(w22, v2, acc[i-2][0])));
            acc[i-2][1] = fmaf(w20, v1, fmaf(w21, v2, fmaf(w22, v3, acc[i-2][1])));
            acc[i-2][2] = fmaf(w20, v2, fmaf(w21, v3, fmaf(w22, v4, acc[i-2][2])));
            acc[i-2][3] = fmaf(w20, v3, fmaf(w21, v4, fmaf(w22, v5, acc[i-2][3])));
        }
    }

    float* po = out + (size_t)plane * PLANE + (y0 + band * 4) * W + x0;
    #pragma unroll
    for (int j = 0; j < 4; ++j) {
        floatx4 o = { acc[j][0], acc[j][1], acc[j][2], acc[j][3] };
        __builtin_nontemporal_store(o, (floatx4*)(po + j * W));
    }
}

extern "C" void kernel_launch(void* const* d_in, const int* in_sizes, int n_in,
                              void* d_out, int out_size, void* d_ws, size_t ws_size,
                              hipStream_t stream) {
    const float* x    = (const float*)d_in[0];
    const float* w1   = (const float*)d_in[1];
    const float* b1   = (const float*)d_in[2];
    const float* w2   = (const float*)d_in[3];
    const float* b2   = (const float*)d_in[4];
    const float* wb   = (const float*)d_in[5];
    const float* bias = (const float*)d_in[6];
    float* out = (float*)d_out;

    float* pooled = (float*)d_ws;          // [2048]
    float* cw     = pooled + NPLANES;      // [2048*9]

    pool_kernel<<<NPLANES, 256, 0, stream>>>(x, pooled);
    selector_kernel<<<1, 512, 0, stream>>>(pooled, w1, b1, w2, b2, wb, cw);
    conv_kernel<<<NPLANES * SEGS, TBLK, 0, stream>>>(x, cw, bias, out);
}